// Round 4
// baseline (230.589 us; speedup 1.0000x reference)
//
#include <hip/hip_runtime.h>
#include <hip/hip_bf16.h>

// B=512, T=2048, S=16, H=128, A=4.  NTOK = 1,048,576 tokens.
// Transposed MFMA chain, v_mfma_f32_16x16x16f16 (K=16: D layout == B layout,
// so chained GEMMs need no data movement; tokens live in lanes).
// Numerics (verified r6/r8/r9/r10, absmax 0.0625): QP-amplified chain
// (z2/sech2/dh/f/G) in split-f16 (hi+lo, 3 MFMAs/product); u_unc chain
// (z1->ua) single f16 (O(1) sensitivity).
// Round-11 structure: single-tile body (r9) + LDS weights/biases, PLUS:
//  (a) __launch_bounds__(256,5): r0/r1 occupancy pinned at 37.5% = 12
//      waves/CU => true per-wave regs ~160 (arch VGPR 56-64 + ~96 AGPR
//      accumulators, unified file). Cap at ~102 total -> 5 waves/SIMD.
//      Spill tripwire: hbm_bytes >> 100MB (r7: cap-102 spill, since fixed
//      by biases-in-LDS).
//  (b) shared-rcp tanh4: four 1/(1+e_i) from ONE v_rcp via prefix/suffix
//      products (trans/tile 128->80; trans were ~half of VALU issue).
//      Error ~1e-6 abs on t2, invisible vs split-f16 2^-11-scale terms.
//      Overflow-safe: product of 4 d's < 3.4e38 for any |z|<10.9.
//  (c) v_cvt_pkrtz packed f32->f16x2 inside split4 (RTZ on hi is
//      residual-compensated by lo -> 2nd-order); toh(t1) stays RTN.
//      [r2 compile fix: builtin returns __fp16x2 — capture with auto,
//       element-cast to _Float16.]
//  (d) u-redq dropped: ua rows>=4 are zero so q0 lanes hold the full
//      answer (old redq was a broadcast); 2x of u_unc folded into packed
//      Wc2 (exact exponent bump in f16).
//  (e) grid-stride, NBLK=2560 (10 blocks/CU): backfills cleanly at any
//      residency 3/4/5; long waves (7 tiles) land on low bids = LPT.
#define HDIM 128
#define SDIM 16
#define ADIM 4
#define NTOK (512 * 2048)
#define NTILE (NTOK / 16)      // 65536 16-token tiles
#define NBLK 2560
#define WPB 4                  // waves per 256-thread block
#define NW (NBLK * WPB)        // 10240 waves; 6-7 tiles per wave

typedef _Float16 half4 __attribute__((ext_vector_type(4)));
typedef float f32x4 __attribute__((ext_vector_type(4)));

__device__ __forceinline__ f32x4 mm(half4 a, half4 b, f32x4 c) {
    return __builtin_amdgcn_mfma_f32_16x16x16f16(a, b, c, 0, 0, 0);
}
// tanh via 1 - 2/(1+e^{2x}); e^{2x} = exp2(x*2log2e).  ONE rcp for all 4
// elements via prefix/suffix products (saves 3 quarter-rate trans ops).
__device__ __forceinline__ f32x4 tanh4(f32x4 z) {
    const float c = 2.88539008177792681f;   // 2*log2(e)
    float d0 = __builtin_amdgcn_exp2f(z.x * c) + 1.0f;
    float d1 = __builtin_amdgcn_exp2f(z.y * c) + 1.0f;
    float d2 = __builtin_amdgcn_exp2f(z.z * c) + 1.0f;
    float d3 = __builtin_amdgcn_exp2f(z.w * c) + 1.0f;
    float p01 = d0 * d1, p23 = d2 * d3;
    float R = __builtin_amdgcn_rcpf(p01 * p23);
    float R01 = R * p23, R23 = R * p01;     // 1/(d0 d1), 1/(d2 d3)
    f32x4 r;
    r.x = 1.0f - 2.0f * (R01 * d1);
    r.y = 1.0f - 2.0f * (R01 * d0);
    r.z = 1.0f - 2.0f * (R23 * d3);
    r.w = 1.0f - 2.0f * (R23 * d2);
    return r;
}
__device__ __forceinline__ half4 toh(f32x4 v) {     // RTN — t1 path
    half4 h;
    h.x = (_Float16)v.x; h.y = (_Float16)v.y;
    h.z = (_Float16)v.z; h.w = (_Float16)v.w;
    return h;
}
__device__ __forceinline__ half4 toh_rtz(f32x4 v) { // packed RTZ, 2 insts
    auto a = __builtin_amdgcn_cvt_pkrtz(v.x, v.y);  // __fp16 x2
    auto b = __builtin_amdgcn_cvt_pkrtz(v.z, v.w);
    half4 h;
    h.x = (_Float16)a.x; h.y = (_Float16)a.y;
    h.z = (_Float16)b.x; h.w = (_Float16)b.y;
    return h;
}
// split fp32 vector into f16 hi + f16 lo (x ~= hi + lo).  RTZ on hi is
// compensated by lo (residual captured exactly to lo's own rounding) —
// total error stays ~2^-21 x, second-order vs the split-f16 MFMA terms.
__device__ __forceinline__ void split4(f32x4 v, half4& hi, half4& lo) {
    hi = toh_rtz(v);
    f32x4 r;
    r.x = v.x - (float)hi.x; r.y = v.y - (float)hi.y;
    r.z = v.z - (float)hi.z; r.w = v.w - (float)hi.w;
    lo = toh_rtz(r);
}
__device__ __forceinline__ float dot4(f32x4 a, f32x4 b) {
    return a.x*b.x + a.y*b.y + a.z*b.z + a.w*b.w;
}
__device__ __forceinline__ float redq(float v) {   // sum over the 4 lane-quads
    v += __shfl_xor(v, 16, 64);
    v += __shfl_xor(v, 32, 64);
    return v;
}

__global__ __launch_bounds__(256, 5) void cbf_qp_kernel(
    const float* __restrict__ state,
    const float* __restrict__ Wc1, const float* __restrict__ bc1,
    const float* __restrict__ Wc2, const float* __restrict__ bc2,
    const float* __restrict__ Wh1, const float* __restrict__ bh1,
    const float* __restrict__ wh2, const float* __restrict__ bh2,
    const float* __restrict__ Wf,  const float* __restrict__ bf,
    const float* __restrict__ Wg,  const float* __restrict__ bg,
    float* __restrict__ out)
{
    // ---- LDS weight A-frags: [chunk][lane] half4 --------------------------
    __shared__ __align__(16) half4 az1_s[8 * 64];    // Wc1^T
    __shared__ __align__(16) half4 aua_s[8 * 64];    // 2*Wc2^T (rows >= 4 zero)
    __shared__ __align__(16) half4 az2h_s[8 * 64];   // Wh1^T hi
    __shared__ __align__(16) half4 az2l_s[8 * 64];   // Wh1^T lo
    __shared__ __align__(16) half4 adhh_s[8 * 64];   // (Wh1 .* wh2) hi
    __shared__ __align__(16) half4 adhl_s[8 * 64];   // (Wh1 .* wh2) lo
    __shared__ __align__(16) half4 afh_s[64];        // Wf^T hi
    __shared__ __align__(16) half4 afl_s[64];        // Wf^T lo
    __shared__ __align__(16) half4 agh_s[4 * 64];    // Wg^T permuted hi
    __shared__ __align__(16) half4 agl_s[4 * 64];    // Wg^T permuted lo
    __shared__ __align__(16) float bgt_s[64];        // bgt[a][s] = bg[s*4+a]
    __shared__ __align__(16) float bc1_s[HDIM];      // biases staged in LDS so
    __shared__ __align__(16) float bh1_s[HDIM];      // the allocator can't hoist
    __shared__ __align__(16) float wh2_s[HDIM];      // loop-invariant loads (r6)

    const int tid = threadIdx.x;

    // ---- per-block pack: raw global weights -> LDS frags ------------------
    // A-frag layout: lane l holds A[m][k], m = l&15, k = (l>>4)*4 + e
    for (int idx = tid; idx < 8 * 64; idx += 256) {
        const int c = idx >> 6, lane = idx & 63;
        const int m = lane & 15, q = lane >> 4;
        half4 hz1, hua, h2h, h2l, hdh, hdl;
        #pragma unroll
        for (int e = 0; e < 4; ++e) {
            const int k = q * 4 + e;
            const int j = c * 16 + k;
            hz1[e] = (_Float16)Wc1[k * HDIM + c*16 + m];
            // 2x folded here (u_unc = 2*(Wc2^T t + bc2)); doubling is exact.
            hua[e] = (m < ADIM) ? (_Float16)(2.0f * Wc2[j * ADIM + m])
                                : (_Float16)0.f;
            float w2 = Wh1[k * HDIM + c*16 + m];
            _Float16 hh = (_Float16)w2;
            h2h[e] = hh; h2l[e] = (_Float16)(w2 - (float)hh);
            float wd = Wh1[m * HDIM + j] * wh2[j];
            _Float16 hd = (_Float16)wd;
            hdh[e] = hd; hdl[e] = (_Float16)(wd - (float)hd);
        }
        az1_s[idx] = hz1;  aua_s[idx] = hua;
        az2h_s[idx] = h2h; az2l_s[idx] = h2l;
        adhh_s[idx] = hdh; adhl_s[idx] = hdl;
    }
    if (tid < 64) {                                  // Wf^T split
        const int m = tid & 15, q = tid >> 4;
        half4 fh, fl;
        #pragma unroll
        for (int e = 0; e < 4; ++e) {
            float w = Wf[(q*4+e) * SDIM + m];
            _Float16 h = (_Float16)w;
            fh[e] = h; fl[e] = (_Float16)(w - (float)h);
        }
        afh_s[tid] = fh; afl_s[tid] = fl;
    }
    {                                                // Wg^T row-permuted split
        const int a = tid >> 6, lane = tid & 63;
        const int m = lane & 15, q = lane >> 4;      // m = s index
        half4 gh, gl;
        #pragma unroll
        for (int e = 0; e < 4; ++e) {
            float w = Wg[(q*4+e) * 64 + m*4 + a];
            _Float16 h = (_Float16)w;
            gh[e] = h; gl[e] = (_Float16)(w - (float)h);
        }
        agh_s[tid] = gh; agl_s[tid] = gl;
    }
    if (tid < 64)                                    // bgt[a][s] = bg[s*4+a]
        bgt_s[(tid >> 4) * 16 + (tid & 15)] = bg[(tid & 15) * 4 + (tid >> 4)];
    if (tid < HDIM) {
        bc1_s[tid] = bc1[tid];
        bh1_s[tid] = bh1[tid];
        wh2_s[tid] = wh2[tid];
    }
    __syncthreads();

    // ---- main: grid-stride over 16-token tiles ----------------------------
    const int lane = tid & 63;
    const int q = lane >> 4, n = lane & 15;
    const int wid = blockIdx.x * WPB + (tid >> 6);

    f32x4 bfC = *(const f32x4*)(bf + q*4);
    f32x4 uaC;                                       // 2*bc2 in q0, else 0
    {
        f32x4 b2 = *(const f32x4*)(bc2);
        uaC.x = q == 0 ? 2.0f*b2.x : 0.f; uaC.y = q == 0 ? 2.0f*b2.y : 0.f;
        uaC.z = q == 0 ? 2.0f*b2.z : 0.f; uaC.w = q == 0 ? 2.0f*b2.w : 0.f;
    }
    const float bh2v = bh2[0];

    for (int tile = wid; tile < NTILE; tile += NW) {
        // B-frag of state^T: lane(q,n) holds state[token n][q*4 .. q*4+3]
        f32x4 sv = *(const f32x4*)(state + (size_t)(tile*16 + n) * SDIM + q*4);
        half4 bsh, bsl;
        split4(sv, bsh, bsl);

        // Split accumulators (r8): dh 3x 8-deep chains, ua 2x, hp 2x.
        f32x4 uaA = uaC, uaB = {0.f, 0.f, 0.f, 0.f};
        f32x4 dhA = {0.f, 0.f, 0.f, 0.f};
        f32x4 dhB = {0.f, 0.f, 0.f, 0.f};
        f32x4 dhC = {0.f, 0.f, 0.f, 0.f};
        float hp0 = 0.f, hp1 = 0.f;
        #pragma unroll 2
        for (int c = 0; c < 8; ++c) {
            // ---- low-precision chain: z1 -> tanh -> ua (O(1) sensitivity)
            f32x4 b1 = *(const f32x4*)(&bc1_s[c*16 + q*4]);
            f32x4 z1 = mm(az1_s[c*64 + lane], bsh, b1);
            half4 t1h = toh(tanh4(z1));
            if (c & 1) uaB = mm(aua_s[c*64 + lane], t1h, uaB);
            else       uaA = mm(aua_s[c*64 + lane], t1h, uaA);

            // ---- high-precision chain: z2 (split x split, 3 MFMAs)
            f32x4 b2v = *(const f32x4*)(&bh1_s[c*16 + q*4]);
            half4 a2h = az2h_s[c*64 + lane];
            f32x4 z2 = mm(a2h, bsl, b2v);
            z2 = mm(az2l_s[c*64 + lane], bsh, z2);
            z2 = mm(a2h, bsh, z2);
            f32x4 t2 = tanh4(z2);
            f32x4 s2;
            s2.x = 1.f - t2.x*t2.x; s2.y = 1.f - t2.y*t2.y;
            s2.z = 1.f - t2.z*t2.z; s2.w = 1.f - t2.w*t2.w;
            half4 s2h, s2l;
            split4(s2, s2h, s2l);
            half4 adh_h = adhh_s[c*64 + lane];
            dhA = mm(adh_h, s2h, dhA);
            dhB = mm(adhl_s[c*64 + lane], s2h, dhB);
            dhC = mm(adh_h, s2l, dhC);

            f32x4 wv = *(const f32x4*)(&wh2_s[c*16 + q*4]);
            if (c & 1) hp1 += dot4(wv, t2);
            else       hp0 += dot4(wv, t2);
        }
        f32x4 ua = uaA + uaB;
        f32x4 dh = dhA + dhB + dhC;
        float hp = hp0 + hp1;

        // f^T (rows = s) and G chunks (chunk a: row s = g[s][a]) — split path
        half4 fh = afh_s[lane], fl = afl_s[lane];
        f32x4 fD = mm(fh, bsl, bfC);
        fD = mm(fl, bsh, fD);
        fD = mm(fh, bsh, fD);

        // right = h + bh2 + dh.f   (partials live in lane-quads; reduce)
        float right = redq(hp + dot4(dh, fD)) + bh2v;

        float l0, l1, l2, l3;
        {
            half4 gh = agh_s[0*64 + lane], gl = agl_s[0*64 + lane];
            f32x4 bgC = *(const f32x4*)(&bgt_s[0*16 + q*4]);
            f32x4 G = mm(gh, bsl, bgC); G = mm(gl, bsh, G); G = mm(gh, bsh, G);
            l0 = -redq(dot4(dh, G));
        }
        {
            half4 gh = agh_s[1*64 + lane], gl = agl_s[1*64 + lane];
            f32x4 bgC = *(const f32x4*)(&bgt_s[1*16 + q*4]);
            f32x4 G = mm(gh, bsl, bgC); G = mm(gl, bsh, G); G = mm(gh, bsh, G);
            l1 = -redq(dot4(dh, G));
        }
        {
            half4 gh = agh_s[2*64 + lane], gl = agl_s[2*64 + lane];
            f32x4 bgC = *(const f32x4*)(&bgt_s[2*16 + q*4]);
            f32x4 G = mm(gh, bsl, bgC); G = mm(gl, bsh, G); G = mm(gh, bsh, G);
            l2 = -redq(dot4(dh, G));
        }
        {
            half4 gh = agh_s[3*64 + lane], gl = agl_s[3*64 + lane];
            f32x4 bgC = *(const f32x4*)(&bgt_s[3*16 + q*4]);
            f32x4 G = mm(gh, bsl, bgC); G = mm(gl, bsh, G); G = mm(gh, bsh, G);
            l3 = -redq(dot4(dh, G));
        }

        // ua rows >= 4 are zero and 2x/bc2 already folded in: q0 lanes hold
        // the complete u_unc — no reduce/broadcast needed (QP + store are
        // q0-only; other quads compute garbage that is never stored).
        float u0 = ua.x, u1 = ua.y, u2 = ua.z, u3 = ua.w;

        float viol = l0*u0 + l1*u1 + l2*u2 + l3*u3 - right;
        float lsq  = l0*l0 + l1*l1 + l2*l2 + l3*l3;
        float lam  = viol > 0.f ? viol / (lsq + 1e-8f) : 0.f;

        if (q == 0) {                      // lanes 0-15 store their token
            f32x4 uo;
            uo.x = u0 - lam*l0; uo.y = u1 - lam*l1;
            uo.z = u2 - lam*l2; uo.w = u3 - lam*l3;
            *(f32x4*)(out + (size_t)(tile*16 + n) * ADIM) = uo;
        }
    }
}

extern "C" void kernel_launch(void* const* d_in, const int* in_sizes, int n_in,
                              void* d_out, int out_size, void* d_ws, size_t ws_size,
                              hipStream_t stream) {
    (void)in_sizes; (void)n_in; (void)d_ws; (void)ws_size; (void)out_size;
    const float* state = (const float*)d_in[0];
    const float* Wc1   = (const float*)d_in[1];
    const float* bc1   = (const float*)d_in[2];
    const float* Wc2   = (const float*)d_in[3];
    const float* bc2   = (const float*)d_in[4];
    const float* Wh1   = (const float*)d_in[5];
    const float* bh1   = (const float*)d_in[6];
    const float* wh2   = (const float*)d_in[7];
    const float* bh2   = (const float*)d_in[8];
    const float* Wf    = (const float*)d_in[9];
    const float* bf    = (const float*)d_in[10];
    const float* Wg    = (const float*)d_in[11];
    const float* bg    = (const float*)d_in[12];
    float* out = (float*)d_out;

    hipLaunchKernelGGL(cbf_qp_kernel, dim3(NBLK), dim3(256), 0, stream,
                       state, Wc1, bc1, Wc2, bc2, Wh1, bh1, wh2, bh2,
                       Wf, bf, Wg, bg, out);
}

// Round 5
// 225.716 us; speedup vs baseline: 1.0216x; 1.0216x over previous
//
#include <hip/hip_runtime.h>
#include <hip/hip_bf16.h>

// B=512, T=2048, S=16, H=128, A=4.  NTOK = 1,048,576 tokens.
// Transposed MFMA chain, v_mfma_f32_16x16x16f16 (K=16: D layout == B layout,
// so chained GEMMs need no data movement; tokens live in lanes).
// Numerics (verified r6/r8/r9/r10 + r4, absmax 0.0625): QP-amplified chain
// (z2/sech2/dh/f/G) in split-f16 (hi+lo, 3 MFMAs/product); u_unc chain
// (z1->ua) single f16 (O(1) sensitivity).
// Round-13 structure: r4 body with __launch_bounds__ reverted to (256,4).
// Register-boundary ledger (measured):
//   (256,4) single-tile body  -> no spill, WRITE = 16 MB exactly   (r0: 141.6us)
//   (256,4) pair-batched body -> spill, WRITE 67 MB                (r1: 141.6us)
//   (256,5) single-tile body  -> spill, WRITE 62 MB, FETCH +20 MB  (r4: 151.5us)
// => accumulator live-set sits AT the 128-reg boundary; any squeeze spills.
// This round isolates the untested VALU cuts at the no-spill point:
//  (b) shared-rcp tanh4: four 1/(1+e_i) from ONE v_rcp via prefix/suffix
//      products (trans/tile 128->80; trans ~half of VALU issue at r0).
//      Error ~1e-6 abs, invisible vs split-f16 2^-11-scale terms.
//  (c) v_cvt_pkrtz packed f32->f16x2 in split4 (RTZ hi compensated by lo).
//  (d) u-redq dropped (ua rows>=4 zero => q0 lanes complete); 2x folded
//      into packed Wc2.
//  (e) grid-stride, NBLK=2560.
// Spill tripwire: WRITE_SIZE >> 16384 KB => revert whatever grew the live-set.
#define HDIM 128
#define SDIM 16
#define ADIM 4
#define NTOK (512 * 2048)
#define NTILE (NTOK / 16)      // 65536 16-token tiles
#define NBLK 2560
#define WPB 4                  // waves per 256-thread block
#define NW (NBLK * WPB)        // 10240 waves; 6-7 tiles per wave

typedef _Float16 half4 __attribute__((ext_vector_type(4)));
typedef float f32x4 __attribute__((ext_vector_type(4)));

__device__ __forceinline__ f32x4 mm(half4 a, half4 b, f32x4 c) {
    return __builtin_amdgcn_mfma_f32_16x16x16f16(a, b, c, 0, 0, 0);
}
// tanh via 1 - 2/(1+e^{2x}); e^{2x} = exp2(x*2log2e).  ONE rcp for all 4
// elements via prefix/suffix products (saves 3 quarter-rate trans ops).
__device__ __forceinline__ f32x4 tanh4(f32x4 z) {
    const float c = 2.88539008177792681f;   // 2*log2(e)
    float d0 = __builtin_amdgcn_exp2f(z.x * c) + 1.0f;
    float d1 = __builtin_amdgcn_exp2f(z.y * c) + 1.0f;
    float d2 = __builtin_amdgcn_exp2f(z.z * c) + 1.0f;
    float d3 = __builtin_amdgcn_exp2f(z.w * c) + 1.0f;
    float p01 = d0 * d1, p23 = d2 * d3;
    float R = __builtin_amdgcn_rcpf(p01 * p23);
    float R01 = R * p23, R23 = R * p01;     // 1/(d0 d1), 1/(d2 d3)
    f32x4 r;
    r.x = 1.0f - 2.0f * (R01 * d1);
    r.y = 1.0f - 2.0f * (R01 * d0);
    r.z = 1.0f - 2.0f * (R23 * d3);
    r.w = 1.0f - 2.0f * (R23 * d2);
    return r;
}
__device__ __forceinline__ half4 toh(f32x4 v) {     // RTN — t1 path
    half4 h;
    h.x = (_Float16)v.x; h.y = (_Float16)v.y;
    h.z = (_Float16)v.z; h.w = (_Float16)v.w;
    return h;
}
__device__ __forceinline__ half4 toh_rtz(f32x4 v) { // packed RTZ, 2 insts
    auto a = __builtin_amdgcn_cvt_pkrtz(v.x, v.y);  // __fp16 x2
    auto b = __builtin_amdgcn_cvt_pkrtz(v.z, v.w);
    half4 h;
    h.x = (_Float16)a.x; h.y = (_Float16)a.y;
    h.z = (_Float16)b.x; h.w = (_Float16)b.y;
    return h;
}
// split fp32 vector into f16 hi + f16 lo (x ~= hi + lo).  RTZ on hi is
// compensated by lo (residual captured exactly to lo's own rounding) —
// total error stays ~2^-21 x, second-order vs the split-f16 MFMA terms.
__device__ __forceinline__ void split4(f32x4 v, half4& hi, half4& lo) {
    hi = toh_rtz(v);
    f32x4 r;
    r.x = v.x - (float)hi.x; r.y = v.y - (float)hi.y;
    r.z = v.z - (float)hi.z; r.w = v.w - (float)hi.w;
    lo = toh_rtz(r);
}
__device__ __forceinline__ float dot4(f32x4 a, f32x4 b) {
    return a.x*b.x + a.y*b.y + a.z*b.z + a.w*b.w;
}
__device__ __forceinline__ float redq(float v) {   // sum over the 4 lane-quads
    v += __shfl_xor(v, 16, 64);
    v += __shfl_xor(v, 32, 64);
    return v;
}

__global__ __launch_bounds__(256, 4) void cbf_qp_kernel(
    const float* __restrict__ state,
    const float* __restrict__ Wc1, const float* __restrict__ bc1,
    const float* __restrict__ Wc2, const float* __restrict__ bc2,
    const float* __restrict__ Wh1, const float* __restrict__ bh1,
    const float* __restrict__ wh2, const float* __restrict__ bh2,
    const float* __restrict__ Wf,  const float* __restrict__ bf,
    const float* __restrict__ Wg,  const float* __restrict__ bg,
    float* __restrict__ out)
{
    // ---- LDS weight A-frags: [chunk][lane] half4 --------------------------
    __shared__ __align__(16) half4 az1_s[8 * 64];    // Wc1^T
    __shared__ __align__(16) half4 aua_s[8 * 64];    // 2*Wc2^T (rows >= 4 zero)
    __shared__ __align__(16) half4 az2h_s[8 * 64];   // Wh1^T hi
    __shared__ __align__(16) half4 az2l_s[8 * 64];   // Wh1^T lo
    __shared__ __align__(16) half4 adhh_s[8 * 64];   // (Wh1 .* wh2) hi
    __shared__ __align__(16) half4 adhl_s[8 * 64];   // (Wh1 .* wh2) lo
    __shared__ __align__(16) half4 afh_s[64];        // Wf^T hi
    __shared__ __align__(16) half4 afl_s[64];        // Wf^T lo
    __shared__ __align__(16) half4 agh_s[4 * 64];    // Wg^T permuted hi
    __shared__ __align__(16) half4 agl_s[4 * 64];    // Wg^T permuted lo
    __shared__ __align__(16) float bgt_s[64];        // bgt[a][s] = bg[s*4+a]
    __shared__ __align__(16) float bc1_s[HDIM];      // biases staged in LDS so
    __shared__ __align__(16) float bh1_s[HDIM];      // the allocator can't hoist
    __shared__ __align__(16) float wh2_s[HDIM];      // loop-invariant loads (r6)

    const int tid = threadIdx.x;

    // ---- per-block pack: raw global weights -> LDS frags ------------------
    // A-frag layout: lane l holds A[m][k], m = l&15, k = (l>>4)*4 + e
    for (int idx = tid; idx < 8 * 64; idx += 256) {
        const int c = idx >> 6, lane = idx & 63;
        const int m = lane & 15, q = lane >> 4;
        half4 hz1, hua, h2h, h2l, hdh, hdl;
        #pragma unroll
        for (int e = 0; e < 4; ++e) {
            const int k = q * 4 + e;
            const int j = c * 16 + k;
            hz1[e] = (_Float16)Wc1[k * HDIM + c*16 + m];
            // 2x folded here (u_unc = 2*(Wc2^T t + bc2)); doubling is exact.
            hua[e] = (m < ADIM) ? (_Float16)(2.0f * Wc2[j * ADIM + m])
                                : (_Float16)0.f;
            float w2 = Wh1[k * HDIM + c*16 + m];
            _Float16 hh = (_Float16)w2;
            h2h[e] = hh; h2l[e] = (_Float16)(w2 - (float)hh);
            float wd = Wh1[m * HDIM + j] * wh2[j];
            _Float16 hd = (_Float16)wd;
            hdh[e] = hd; hdl[e] = (_Float16)(wd - (float)hd);
        }
        az1_s[idx] = hz1;  aua_s[idx] = hua;
        az2h_s[idx] = h2h; az2l_s[idx] = h2l;
        adhh_s[idx] = hdh; adhl_s[idx] = hdl;
    }
    if (tid < 64) {                                  // Wf^T split
        const int m = tid & 15, q = tid >> 4;
        half4 fh, fl;
        #pragma unroll
        for (int e = 0; e < 4; ++e) {
            float w = Wf[(q*4+e) * SDIM + m];
            _Float16 h = (_Float16)w;
            fh[e] = h; fl[e] = (_Float16)(w - (float)h);
        }
        afh_s[tid] = fh; afl_s[tid] = fl;
    }
    {                                                // Wg^T row-permuted split
        const int a = tid >> 6, lane = tid & 63;
        const int m = lane & 15, q = lane >> 4;      // m = s index
        half4 gh, gl;
        #pragma unroll
        for (int e = 0; e < 4; ++e) {
            float w = Wg[(q*4+e) * 64 + m*4 + a];
            _Float16 h = (_Float16)w;
            gh[e] = h; gl[e] = (_Float16)(w - (float)h);
        }
        agh_s[tid] = gh; agl_s[tid] = gl;
    }
    if (tid < 64)                                    // bgt[a][s] = bg[s*4+a]
        bgt_s[(tid >> 4) * 16 + (tid & 15)] = bg[(tid & 15) * 4 + (tid >> 4)];
    if (tid < HDIM) {
        bc1_s[tid] = bc1[tid];
        bh1_s[tid] = bh1[tid];
        wh2_s[tid] = wh2[tid];
    }
    __syncthreads();

    // ---- main: grid-stride over 16-token tiles ----------------------------
    const int lane = tid & 63;
    const int q = lane >> 4, n = lane & 15;
    const int wid = blockIdx.x * WPB + (tid >> 6);

    f32x4 bfC = *(const f32x4*)(bf + q*4);
    f32x4 uaC;                                       // 2*bc2 in q0, else 0
    {
        f32x4 b2 = *(const f32x4*)(bc2);
        uaC.x = q == 0 ? 2.0f*b2.x : 0.f; uaC.y = q == 0 ? 2.0f*b2.y : 0.f;
        uaC.z = q == 0 ? 2.0f*b2.z : 0.f; uaC.w = q == 0 ? 2.0f*b2.w : 0.f;
    }
    const float bh2v = bh2[0];

    for (int tile = wid; tile < NTILE; tile += NW) {
        // B-frag of state^T: lane(q,n) holds state[token n][q*4 .. q*4+3]
        f32x4 sv = *(const f32x4*)(state + (size_t)(tile*16 + n) * SDIM + q*4);
        half4 bsh, bsl;
        split4(sv, bsh, bsl);

        // Split accumulators (r8): dh 3x 8-deep chains, ua 2x, hp 2x.
        f32x4 uaA = uaC, uaB = {0.f, 0.f, 0.f, 0.f};
        f32x4 dhA = {0.f, 0.f, 0.f, 0.f};
        f32x4 dhB = {0.f, 0.f, 0.f, 0.f};
        f32x4 dhC = {0.f, 0.f, 0.f, 0.f};
        float hp0 = 0.f, hp1 = 0.f;
        #pragma unroll 2
        for (int c = 0; c < 8; ++c) {
            // ---- low-precision chain: z1 -> tanh -> ua (O(1) sensitivity)
            f32x4 b1 = *(const f32x4*)(&bc1_s[c*16 + q*4]);
            f32x4 z1 = mm(az1_s[c*64 + lane], bsh, b1);
            half4 t1h = toh(tanh4(z1));
            if (c & 1) uaB = mm(aua_s[c*64 + lane], t1h, uaB);
            else       uaA = mm(aua_s[c*64 + lane], t1h, uaA);

            // ---- high-precision chain: z2 (split x split, 3 MFMAs)
            f32x4 b2v = *(const f32x4*)(&bh1_s[c*16 + q*4]);
            half4 a2h = az2h_s[c*64 + lane];
            f32x4 z2 = mm(a2h, bsl, b2v);
            z2 = mm(az2l_s[c*64 + lane], bsh, z2);
            z2 = mm(a2h, bsh, z2);
            f32x4 t2 = tanh4(z2);
            f32x4 s2;
            s2.x = 1.f - t2.x*t2.x; s2.y = 1.f - t2.y*t2.y;
            s2.z = 1.f - t2.z*t2.z; s2.w = 1.f - t2.w*t2.w;
            half4 s2h, s2l;
            split4(s2, s2h, s2l);
            half4 adh_h = adhh_s[c*64 + lane];
            dhA = mm(adh_h, s2h, dhA);
            dhB = mm(adhl_s[c*64 + lane], s2h, dhB);
            dhC = mm(adh_h, s2l, dhC);

            f32x4 wv = *(const f32x4*)(&wh2_s[c*16 + q*4]);
            if (c & 1) hp1 += dot4(wv, t2);
            else       hp0 += dot4(wv, t2);
        }
        f32x4 ua = uaA + uaB;
        f32x4 dh = dhA + dhB + dhC;
        float hp = hp0 + hp1;

        // f^T (rows = s) and G chunks (chunk a: row s = g[s][a]) — split path
        half4 fh = afh_s[lane], fl = afl_s[lane];
        f32x4 fD = mm(fh, bsl, bfC);
        fD = mm(fl, bsh, fD);
        fD = mm(fh, bsh, fD);

        // right = h + bh2 + dh.f   (partials live in lane-quads; reduce)
        float right = redq(hp + dot4(dh, fD)) + bh2v;

        float l0, l1, l2, l3;
        {
            half4 gh = agh_s[0*64 + lane], gl = agl_s[0*64 + lane];
            f32x4 bgC = *(const f32x4*)(&bgt_s[0*16 + q*4]);
            f32x4 G = mm(gh, bsl, bgC); G = mm(gl, bsh, G); G = mm(gh, bsh, G);
            l0 = -redq(dot4(dh, G));
        }
        {
            half4 gh = agh_s[1*64 + lane], gl = agl_s[1*64 + lane];
            f32x4 bgC = *(const f32x4*)(&bgt_s[1*16 + q*4]);
            f32x4 G = mm(gh, bsl, bgC); G = mm(gl, bsh, G); G = mm(gh, bsh, G);
            l1 = -redq(dot4(dh, G));
        }
        {
            half4 gh = agh_s[2*64 + lane], gl = agl_s[2*64 + lane];
            f32x4 bgC = *(const f32x4*)(&bgt_s[2*16 + q*4]);
            f32x4 G = mm(gh, bsl, bgC); G = mm(gl, bsh, G); G = mm(gh, bsh, G);
            l2 = -redq(dot4(dh, G));
        }
        {
            half4 gh = agh_s[3*64 + lane], gl = agl_s[3*64 + lane];
            f32x4 bgC = *(const f32x4*)(&bgt_s[3*16 + q*4]);
            f32x4 G = mm(gh, bsl, bgC); G = mm(gl, bsh, G); G = mm(gh, bsh, G);
            l3 = -redq(dot4(dh, G));
        }

        // ua rows >= 4 are zero and 2x/bc2 already folded in: q0 lanes hold
        // the complete u_unc — no reduce/broadcast needed (QP + store are
        // q0-only; other quads compute garbage that is never stored).
        float u0 = ua.x, u1 = ua.y, u2 = ua.z, u3 = ua.w;

        float viol = l0*u0 + l1*u1 + l2*u2 + l3*u3 - right;
        float lsq  = l0*l0 + l1*l1 + l2*l2 + l3*l3;
        float lam  = viol > 0.f ? viol / (lsq + 1e-8f) : 0.f;

        if (q == 0) {                      // lanes 0-15 store their token
            f32x4 uo;
            uo.x = u0 - lam*l0; uo.y = u1 - lam*l1;
            uo.z = u2 - lam*l2; uo.w = u3 - lam*l3;
            *(f32x4*)(out + (size_t)(tile*16 + n) * ADIM) = uo;
        }
    }
}

extern "C" void kernel_launch(void* const* d_in, const int* in_sizes, int n_in,
                              void* d_out, int out_size, void* d_ws, size_t ws_size,
                              hipStream_t stream) {
    (void)in_sizes; (void)n_in; (void)d_ws; (void)ws_size; (void)out_size;
    const float* state = (const float*)d_in[0];
    const float* Wc1   = (const float*)d_in[1];
    const float* bc1   = (const float*)d_in[2];
    const float* Wc2   = (const float*)d_in[3];
    const float* bc2   = (const float*)d_in[4];
    const float* Wh1   = (const float*)d_in[5];
    const float* bh1   = (const float*)d_in[6];
    const float* wh2   = (const float*)d_in[7];
    const float* bh2   = (const float*)d_in[8];
    const float* Wf    = (const float*)d_in[9];
    const float* bf    = (const float*)d_in[10];
    const float* Wg    = (const float*)d_in[11];
    const float* bg    = (const float*)d_in[12];
    float* out = (float*)d_out;

    hipLaunchKernelGGL(cbf_qp_kernel, dim3(NBLK), dim3(256), 0, stream,
                       state, Wc1, bc1, Wc2, bc2, Wh1, bh1, wh2, bh2,
                       Wf, bf, Wg, bg, out);
}

// Round 7
// 211.814 us; speedup vs baseline: 1.0886x; 1.0656x over previous
//
#include <hip/hip_runtime.h>
#include <hip/hip_bf16.h>

// B=512, T=2048, S=16, H=128, A=4.  NTOK = 1,048,576 tokens.
// Transposed MFMA chain, v_mfma_f32_16x16x16f16 (K=16: D layout == B layout).
// Numerics (verified r6/r8/r9/r10/r4/r5, absmax 0.0625): QP-amplified chain
// (z2/sech2/dh/f/G) in split-f16 (hi+lo, 3 MFMAs/product); u_unc chain
// (z1->ua) single f16.
// Register-boundary ledger (measured):
//   (256,4) single-tile body  -> no spill, WRITE = 16 MB exactly   (r0: 141.6us)
//   (256,4) pair-batched body -> spill, WRITE 67 MB                (r1: 141.6us)
//   (256,5) single-tile body  -> spill, WRITE 62 MB, FETCH +20 MB  (r4: 151.5us)
// VALU ledger (measured r5): VALU-busy cycles invariant under trans<->mul
// swaps; the issue-slot cost is the SCAFFOLDING. This round deletes it
// algebraically (all exact or tighter):
//  (f) 2log2(e) folded into packed Wc1/Wh1/bc1/bh1 -> MFMA output is the
//      exp2 argument directly (kills 32 muls/tile; one FEWER rounding).
//  (g) R-form: R = rcp(2^z'+1); t = 1-2R; sech2 = 4R(1-R):
//        s2' = fma(-R,R,R) = sech2/4, the 4 folded into packed adh/adl
//        (exact exponent shift).  fma form is exact-product -> tighter
//        than 1-t^2 near saturation.  t2 never materialized.
//      hp: sum(wh2*t2) = W2B - sum(2*wh2 * R); W2B = sum(wh2)+bh2 packed
//        once; the 2 folded into wh2_s.  right = W2B + redq(dh.f - hpR).
//  (h) lam via v_rcp (2^-22 rel) instead of full-precision divide.
//  (i) NBLK back to 2048: exact 8 tiles/wave (r5's 2560 -> 6.4 avg/7 max
//      = ~9% tail loss), contiguous r0-style tile loop.
// Kept from r5: pkrtz split4, u-redq drop + 2x-in-Wc2, biases in LDS,
// (256,4).  Spill tripwire: WRITE_SIZE >> 16384 KB.
#define HDIM 128
#define SDIM 16
#define ADIM 4
#define NTOK (512 * 2048)
#define NTILE (NTOK / 16)      // 65536 16-token tiles
#define NBLK 2048
#define WPB 4                  // waves per 256-thread block
#define TPW (NTILE / (NBLK * WPB))   // 8 tiles per wave

#define KC 2.88539008177792681f      // 2*log2(e)

typedef _Float16 half4 __attribute__((ext_vector_type(4)));
typedef float f32x4 __attribute__((ext_vector_type(4)));

__device__ __forceinline__ f32x4 mm(half4 a, half4 b, f32x4 c) {
    return __builtin_amdgcn_mfma_f32_16x16x16f16(a, b, c, 0, 0, 0);
}
// R = 1/(2^z + 1), per element (z is PRE-SCALED by 2log2e via the weights).
// tanh(x) = 1 - 2R;  sech^2(x) = 4R(1-R).
__device__ __forceinline__ f32x4 sigR4(f32x4 z) {
    f32x4 r;
    r.x = __builtin_amdgcn_rcpf(__builtin_amdgcn_exp2f(z.x) + 1.0f);
    r.y = __builtin_amdgcn_rcpf(__builtin_amdgcn_exp2f(z.y) + 1.0f);
    r.z = __builtin_amdgcn_rcpf(__builtin_amdgcn_exp2f(z.z) + 1.0f);
    r.w = __builtin_amdgcn_rcpf(__builtin_amdgcn_exp2f(z.w) + 1.0f);
    return r;
}
__device__ __forceinline__ half4 toh(f32x4 v) {     // RTN — t1 path
    half4 h;
    h.x = (_Float16)v.x; h.y = (_Float16)v.y;
    h.z = (_Float16)v.z; h.w = (_Float16)v.w;
    return h;
}
__device__ __forceinline__ half4 toh_rtz(f32x4 v) { // packed RTZ, 2 insts
    auto a = __builtin_amdgcn_cvt_pkrtz(v.x, v.y);  // __fp16 x2
    auto b = __builtin_amdgcn_cvt_pkrtz(v.z, v.w);
    half4 h;
    h.x = (_Float16)a.x; h.y = (_Float16)a.y;
    h.z = (_Float16)b.x; h.w = (_Float16)b.y;
    return h;
}
// split fp32 vector into f16 hi + f16 lo (x ~= hi + lo).  RTZ on hi is
// compensated by lo — total error ~2^-21 x (verified r5).
__device__ __forceinline__ void split4(f32x4 v, half4& hi, half4& lo) {
    hi = toh_rtz(v);
    f32x4 r;
    r.x = v.x - (float)hi.x; r.y = v.y - (float)hi.y;
    r.z = v.z - (float)hi.z; r.w = v.w - (float)hi.w;
    lo = toh_rtz(r);
}
__device__ __forceinline__ float dot4(f32x4 a, f32x4 b) {
    return a.x*b.x + a.y*b.y + a.z*b.z + a.w*b.w;
}
__device__ __forceinline__ float redq(float v) {   // sum over the 4 lane-quads
    v += __shfl_xor(v, 16, 64);
    v += __shfl_xor(v, 32, 64);
    return v;
}

__global__ __launch_bounds__(256, 4) void cbf_qp_kernel(
    const float* __restrict__ state,
    const float* __restrict__ Wc1, const float* __restrict__ bc1,
    const float* __restrict__ Wc2, const float* __restrict__ bc2,
    const float* __restrict__ Wh1, const float* __restrict__ bh1,
    const float* __restrict__ wh2, const float* __restrict__ bh2,
    const float* __restrict__ Wf,  const float* __restrict__ bf,
    const float* __restrict__ Wg,  const float* __restrict__ bg,
    float* __restrict__ out)
{
    // ---- LDS weight A-frags: [chunk][lane] half4 --------------------------
    __shared__ __align__(16) half4 az1_s[8 * 64];    // KC*Wc1^T
    __shared__ __align__(16) half4 aua_s[8 * 64];    // 2*Wc2^T (rows >= 4 zero)
    __shared__ __align__(16) half4 az2h_s[8 * 64];   // KC*Wh1^T hi
    __shared__ __align__(16) half4 az2l_s[8 * 64];   // KC*Wh1^T lo
    __shared__ __align__(16) half4 adhh_s[8 * 64];   // 4*(Wh1 .* wh2) hi
    __shared__ __align__(16) half4 adhl_s[8 * 64];   // 4*(Wh1 .* wh2) lo
    __shared__ __align__(16) half4 afh_s[64];        // Wf^T hi
    __shared__ __align__(16) half4 afl_s[64];        // Wf^T lo
    __shared__ __align__(16) half4 agh_s[4 * 64];    // Wg^T permuted hi
    __shared__ __align__(16) half4 agl_s[4 * 64];    // Wg^T permuted lo
    __shared__ __align__(16) float bgt_s[64];        // bgt[a][s] = bg[s*4+a]
    __shared__ __align__(16) float bc1_s[HDIM];      // KC*bc1
    __shared__ __align__(16) float bh1_s[HDIM];      // KC*bh1
    __shared__ __align__(16) float wh2_s[HDIM];      // 2*wh2
    __shared__ float w2b_s;                          // sum(wh2) + bh2

    const int tid = threadIdx.x;

    // ---- per-block pack: raw global weights -> LDS frags ------------------
    // A-frag layout: lane l holds A[m][k], m = l&15, k = (l>>4)*4 + e
    for (int idx = tid; idx < 8 * 64; idx += 256) {
        const int c = idx >> 6, lane = idx & 63;
        const int m = lane & 15, q = lane >> 4;
        half4 hz1, hua, h2h, h2l, hdh, hdl;
        #pragma unroll
        for (int e = 0; e < 4; ++e) {
            const int k = q * 4 + e;
            const int j = c * 16 + k;
            hz1[e] = (_Float16)(KC * Wc1[k * HDIM + c*16 + m]);
            // 2x folded (u_unc = 2*(Wc2^T t + bc2)); doubling exact.
            hua[e] = (m < ADIM) ? (_Float16)(2.0f * Wc2[j * ADIM + m])
                                : (_Float16)0.f;
            float w2 = KC * Wh1[k * HDIM + c*16 + m];
            _Float16 hh = (_Float16)w2;
            h2h[e] = hh; h2l[e] = (_Float16)(w2 - (float)hh);
            float wd = 4.0f * Wh1[m * HDIM + j] * wh2[j];   // 4x: sech2 = 4*s2'
            _Float16 hd = (_Float16)wd;
            hdh[e] = hd; hdl[e] = (_Float16)(wd - (float)hd);
        }
        az1_s[idx] = hz1;  aua_s[idx] = hua;
        az2h_s[idx] = h2h; az2l_s[idx] = h2l;
        adhh_s[idx] = hdh; adhl_s[idx] = hdl;
    }
    if (tid < 64) {                                  // Wf^T split
        const int m = tid & 15, q = tid >> 4;
        half4 fh, fl;
        #pragma unroll
        for (int e = 0; e < 4; ++e) {
            float w = Wf[(q*4+e) * SDIM + m];
            _Float16 h = (_Float16)w;
            fh[e] = h; fl[e] = (_Float16)(w - (float)h);
        }
        afh_s[tid] = fh; afl_s[tid] = fl;
    }
    {                                                // Wg^T row-permuted split
        const int a = tid >> 6, lane = tid & 63;
        const int m = lane & 15, q = lane >> 4;      // m = s index
        half4 gh, gl;
        #pragma unroll
        for (int e = 0; e < 4; ++e) {
            float w = Wg[(q*4+e) * 64 + m*4 + a];
            _Float16 h = (_Float16)w;
            gh[e] = h; gl[e] = (_Float16)(w - (float)h);
        }
        agh_s[tid] = gh; agl_s[tid] = gl;
    }
    if (tid < 64)                                    // bgt[a][s] = bg[s*4+a]
        bgt_s[(tid >> 4) * 16 + (tid & 15)] = bg[(tid & 15) * 4 + (tid >> 4)];
    if (tid < HDIM) {
        bc1_s[tid] = KC * bc1[tid];
        bh1_s[tid] = KC * bh1[tid];
        wh2_s[tid] = 2.0f * wh2[tid];
    }
    if (tid == 0) {                                  // W2B = sum(wh2)+bh2
        float s = bh2[0];
        for (int j = 0; j < HDIM; ++j) s += wh2[j];
        w2b_s = s;
    }
    __syncthreads();

    // ---- main: 8 contiguous 16-token tiles per wave -----------------------
    const int lane = tid & 63;
    const int q = lane >> 4, n = lane & 15;
    const int wid = blockIdx.x * WPB + (tid >> 6);

    f32x4 bfC = *(const f32x4*)(bf + q*4);
    f32x4 uaC;                                       // 2*bc2 in q0, else 0
    {
        f32x4 b2 = *(const f32x4*)(bc2);
        uaC.x = q == 0 ? 2.0f*b2.x : 0.f; uaC.y = q == 0 ? 2.0f*b2.y : 0.f;
        uaC.z = q == 0 ? 2.0f*b2.z : 0.f; uaC.w = q == 0 ? 2.0f*b2.w : 0.f;
    }
    const float w2b = w2b_s;

    for (int it = 0; it < TPW; ++it) {
        const int tile = wid * TPW + it;
        // B-frag of state^T: lane(q,n) holds state[token n][q*4 .. q*4+3]
        f32x4 sv = *(const f32x4*)(state + (size_t)(tile*16 + n) * SDIM + q*4);
        half4 bsh, bsl;
        split4(sv, bsh, bsl);

        // Split accumulators (r8): dh 3x 8-deep chains, ua 2x, hp 2x.
        f32x4 uaA = uaC, uaB = {0.f, 0.f, 0.f, 0.f};
        f32x4 dhA = {0.f, 0.f, 0.f, 0.f};
        f32x4 dhB = {0.f, 0.f, 0.f, 0.f};
        f32x4 dhC = {0.f, 0.f, 0.f, 0.f};
        float hp0 = 0.f, hp1 = 0.f;                  // accumulate (2wh2).R
        #pragma unroll 2
        for (int c = 0; c < 8; ++c) {
            // ---- low-precision chain: z1' -> R1 -> t1 -> ua
            f32x4 b1 = *(const f32x4*)(&bc1_s[c*16 + q*4]);
            f32x4 z1 = mm(az1_s[c*64 + lane], bsh, b1);   // = 2log2e * z1
            f32x4 R1 = sigR4(z1);
            f32x4 t1;
            t1.x = __builtin_fmaf(-2.0f, R1.x, 1.0f);
            t1.y = __builtin_fmaf(-2.0f, R1.y, 1.0f);
            t1.z = __builtin_fmaf(-2.0f, R1.z, 1.0f);
            t1.w = __builtin_fmaf(-2.0f, R1.w, 1.0f);
            half4 t1h = toh(t1);
            if (c & 1) uaB = mm(aua_s[c*64 + lane], t1h, uaB);
            else       uaA = mm(aua_s[c*64 + lane], t1h, uaA);

            // ---- high-precision chain: z2' (split x split, 3 MFMAs)
            f32x4 b2v = *(const f32x4*)(&bh1_s[c*16 + q*4]);
            half4 a2h = az2h_s[c*64 + lane];
            f32x4 z2 = mm(a2h, bsl, b2v);
            z2 = mm(az2l_s[c*64 + lane], bsh, z2);
            z2 = mm(a2h, bsh, z2);                        // = 2log2e * z2
            f32x4 R2 = sigR4(z2);
            // s2' = R(1-R) = sech^2/4 (4 folded into adh);  exact-product fma
            f32x4 s2;
            s2.x = __builtin_fmaf(-R2.x, R2.x, R2.x);
            s2.y = __builtin_fmaf(-R2.y, R2.y, R2.y);
            s2.z = __builtin_fmaf(-R2.z, R2.z, R2.z);
            s2.w = __builtin_fmaf(-R2.w, R2.w, R2.w);
            half4 s2h, s2l;
            split4(s2, s2h, s2l);
            half4 adh_h = adhh_s[c*64 + lane];
            dhA = mm(adh_h, s2h, dhA);
            dhB = mm(adhl_s[c*64 + lane], s2h, dhB);
            dhC = mm(adh_h, s2l, dhC);

            // hp partial: (2wh2).R   (hp = W2B - redq(this) later)
            f32x4 wv = *(const f32x4*)(&wh2_s[c*16 + q*4]);
            if (c & 1) hp1 += dot4(wv, R2);
            else       hp0 += dot4(wv, R2);
        }
        f32x4 ua = uaA + uaB;
        f32x4 dh = dhA + dhB + dhC;
        float hp = hp0 + hp1;

        // f^T (rows = s) — split path
        half4 fh = afh_s[lane], fl = afl_s[lane];
        f32x4 fD = mm(fh, bsl, bfC);
        fD = mm(fl, bsh, fD);
        fD = mm(fh, bsh, fD);

        // right = sum(wh2*t2) + bh2 + dh.f = W2B + redq(dh.f - (2wh2).R)
        float right = w2b + redq(dot4(dh, fD) - hp);

        float l0, l1, l2, l3;
        {
            half4 gh = agh_s[0*64 + lane], gl = agl_s[0*64 + lane];
            f32x4 bgC = *(const f32x4*)(&bgt_s[0*16 + q*4]);
            f32x4 G = mm(gh, bsl, bgC); G = mm(gl, bsh, G); G = mm(gh, bsh, G);
            l0 = -redq(dot4(dh, G));
        }
        {
            half4 gh = agh_s[1*64 + lane], gl = agl_s[1*64 + lane];
            f32x4 bgC = *(const f32x4*)(&bgt_s[1*16 + q*4]);
            f32x4 G = mm(gh, bsl, bgC); G = mm(gl, bsh, G); G = mm(gh, bsh, G);
            l1 = -redq(dot4(dh, G));
        }
        {
            half4 gh = agh_s[2*64 + lane], gl = agl_s[2*64 + lane];
            f32x4 bgC = *(const f32x4*)(&bgt_s[2*16 + q*4]);
            f32x4 G = mm(gh, bsl, bgC); G = mm(gl, bsh, G); G = mm(gh, bsh, G);
            l2 = -redq(dot4(dh, G));
        }
        {
            half4 gh = agh_s[3*64 + lane], gl = agl_s[3*64 + lane];
            f32x4 bgC = *(const f32x4*)(&bgt_s[3*16 + q*4]);
            f32x4 G = mm(gh, bsl, bgC); G = mm(gl, bsh, G); G = mm(gh, bsh, G);
            l3 = -redq(dot4(dh, G));
        }

        // ua rows >= 4 zero, 2x/bc2 folded: q0 lanes hold complete u_unc.
        float u0 = ua.x, u1 = ua.y, u2 = ua.z, u3 = ua.w;

        float viol = l0*u0 + l1*u1 + l2*u2 + l3*u3 - right;
        float lsq  = l0*l0 + l1*l1 + l2*l2 + l3*l3;
        float lam  = viol > 0.f
                   ? viol * __builtin_amdgcn_rcpf(lsq + 1e-8f) : 0.f;

        if (q == 0) {                      // lanes 0-15 store their token
            f32x4 uo;
            uo.x = u0 - lam*l0; uo.y = u1 - lam*l1;
            uo.z = u2 - lam*l2; uo.w = u3 - lam*l3;
            *(f32x4*)(out + (size_t)(tile*16 + n) * ADIM) = uo;
        }
    }
}

extern "C" void kernel_launch(void* const* d_in, const int* in_sizes, int n_in,
                              void* d_out, int out_size, void* d_ws, size_t ws_size,
                              hipStream_t stream) {
    (void)in_sizes; (void)n_in; (void)d_ws; (void)ws_size; (void)out_size;
    const float* state = (const float*)d_in[0];
    const float* Wc1   = (const float*)d_in[1];
    const float* bc1   = (const float*)d_in[2];
    const float* Wc2   = (const float*)d_in[3];
    const float* bc2   = (const float*)d_in[4];
    const float* Wh1   = (const float*)d_in[5];
    const float* bh1   = (const float*)d_in[6];
    const float* wh2   = (const float*)d_in[7];
    const float* bh2   = (const float*)d_in[8];
    const float* Wf    = (const float*)d_in[9];
    const float* bf    = (const float*)d_in[10];
    const float* Wg    = (const float*)d_in[11];
    const float* bg    = (const float*)d_in[12];
    float* out = (float*)d_out;

    hipLaunchKernelGGL(cbf_qp_kernel, dim3(NBLK), dim3(256), 0, stream,
                       state, Wc1, bc1, Wc2, bc2, Wh1, bh1, wh2, bh2,
                       Wf, bf, Wg, bg, out);
}

// Round 8
// 202.249 us; speedup vs baseline: 1.1401x; 1.0473x over previous
//
#include <hip/hip_runtime.h>
#include <hip/hip_bf16.h>

// B=512, T=2048, S=16, H=128, A=4.  NTOK = 1,048,576 tokens.
// Transposed MFMA chain, v_mfma_f32_16x16x16f16 (K=16: D layout == B layout).
// Numerics (verified through r7, absmax 0.03125): QP-amplified chain
// (z2/sech2/dh/f/G) in split-f16 (hi+lo, 3 MFMAs/product); u_unc chain
// single f16.
// Ledger (measured):
//   (256,4) single-tile body -> no spill, WRITE = 16 MB exactly (r0/r5/r7)
//   any live-set growth (pair-batch r1, cap-5 r4, cap-102 r7hist) -> spill
//   VALU removal rate: ~2 cyc/inst (r7: −200 inst -> −11.5 us)
//   machine issue-saturated: VALU 70 + MFMA 28 = 98 (r7)
//   trans floor: 64 exp + 64 rcp /tile = the actual 268M sigmoids; ~28 us wall
// Round-15 (this file): feed MFMAs with R directly + MFMA-ize hp + reg diet.
//  (j) ua = (2*Wc2^T.1 + 2*bc2) - 4*Wc2^T R1: const packed into ua0_s;
//      A-frag = -4Wc2^T; B = toh_rtz(R1).  Deletes t1 fmas (-32/tile),
//      RTN cvt -> pkrtz (-16/tile).  Exact algebra; f16 rounding same order.
//  (k) hp = sum(2wh2 * R2) via MFMA: A = row0-only (2wh2 chunk), B =
//      toh_rtz(R2) (z2's D layout IS a valid B-frag: k=(l>>4)*4+e).
//      Deletes both hp dot4 chains (-32 fma/tile), +8 MFMA (pipe has room).
//      hp lands complete in q0 lanes' .x (rows 1-15 of A are zero).
//      right = w2b - hp + redq(dh.f).
//  (l) accumulator diet: single ua chain, dhB+dhC merged (full chunk of
//      indep work between the two dependent MFMAs), hp regs gone.
//      ~-6 live regs; occupancy cliff at total<=128 (3->4 waves/SIMD).
// Kept: KC fold, R-form sech2 via fma(-R,R,R), pkrtz split4, rcp-lam,
// NBLK=2048 (exact 8 tiles/wave), biases in LDS, (256,4).
// Spill tripwire: WRITE_SIZE >> 16384 KB.
#define HDIM 128
#define SDIM 16
#define ADIM 4
#define NTOK (512 * 2048)
#define NTILE (NTOK / 16)      // 65536 16-token tiles
#define NBLK 2048
#define WPB 4                  // waves per 256-thread block
#define TPW (NTILE / (NBLK * WPB))   // 8 tiles per wave

#define KC 2.88539008177792681f      // 2*log2(e)

typedef _Float16 half4 __attribute__((ext_vector_type(4)));
typedef float f32x4 __attribute__((ext_vector_type(4)));

__device__ __forceinline__ f32x4 mm(half4 a, half4 b, f32x4 c) {
    return __builtin_amdgcn_mfma_f32_16x16x16f16(a, b, c, 0, 0, 0);
}
// R = 1/(2^z + 1), per element (z PRE-SCALED by 2log2e via packed weights).
// tanh(x) = 1 - 2R;  sech^2(x) = 4R(1-R).
__device__ __forceinline__ f32x4 sigR4(f32x4 z) {
    f32x4 r;
    r.x = __builtin_amdgcn_rcpf(__builtin_amdgcn_exp2f(z.x) + 1.0f);
    r.y = __builtin_amdgcn_rcpf(__builtin_amdgcn_exp2f(z.y) + 1.0f);
    r.z = __builtin_amdgcn_rcpf(__builtin_amdgcn_exp2f(z.z) + 1.0f);
    r.w = __builtin_amdgcn_rcpf(__builtin_amdgcn_exp2f(z.w) + 1.0f);
    return r;
}
__device__ __forceinline__ half4 toh_rtz(f32x4 v) { // packed RTZ, 2 insts
    auto a = __builtin_amdgcn_cvt_pkrtz(v.x, v.y);  // __fp16 x2
    auto b = __builtin_amdgcn_cvt_pkrtz(v.z, v.w);
    half4 h;
    h.x = (_Float16)a.x; h.y = (_Float16)a.y;
    h.z = (_Float16)b.x; h.w = (_Float16)b.y;
    return h;
}
// split fp32 vector into f16 hi + f16 lo (x ~= hi + lo).  RTZ on hi is
// compensated by lo — total error ~2^-21 x (verified r5/r7).
__device__ __forceinline__ void split4(f32x4 v, half4& hi, half4& lo) {
    hi = toh_rtz(v);
    f32x4 r;
    r.x = v.x - (float)hi.x; r.y = v.y - (float)hi.y;
    r.z = v.z - (float)hi.z; r.w = v.w - (float)hi.w;
    lo = toh_rtz(r);
}
__device__ __forceinline__ float dot4(f32x4 a, f32x4 b) {
    return a.x*b.x + a.y*b.y + a.z*b.z + a.w*b.w;
}
__device__ __forceinline__ float redq(float v) {   // sum over the 4 lane-quads
    v += __shfl_xor(v, 16, 64);
    v += __shfl_xor(v, 32, 64);
    return v;
}

__global__ __launch_bounds__(256, 4) void cbf_qp_kernel(
    const float* __restrict__ state,
    const float* __restrict__ Wc1, const float* __restrict__ bc1,
    const float* __restrict__ Wc2, const float* __restrict__ bc2,
    const float* __restrict__ Wh1, const float* __restrict__ bh1,
    const float* __restrict__ wh2, const float* __restrict__ bh2,
    const float* __restrict__ Wf,  const float* __restrict__ bf,
    const float* __restrict__ Wg,  const float* __restrict__ bg,
    float* __restrict__ out)
{
    // ---- LDS weight A-frags: [chunk][lane] half4 --------------------------
    __shared__ __align__(16) half4 az1_s[8 * 64];    // KC*Wc1^T
    __shared__ __align__(16) half4 aua_s[8 * 64];    // -4*Wc2^T (rows >= 4 zero)
    __shared__ __align__(16) half4 ahp_s[8 * 64];    // 2*wh2 in row 0, else 0
    __shared__ __align__(16) half4 az2h_s[8 * 64];   // KC*Wh1^T hi
    __shared__ __align__(16) half4 az2l_s[8 * 64];   // KC*Wh1^T lo
    __shared__ __align__(16) half4 adhh_s[8 * 64];   // 4*(Wh1 .* wh2) hi
    __shared__ __align__(16) half4 adhl_s[8 * 64];   // 4*(Wh1 .* wh2) lo
    __shared__ __align__(16) half4 afh_s[64];        // Wf^T hi
    __shared__ __align__(16) half4 afl_s[64];        // Wf^T lo
    __shared__ __align__(16) half4 agh_s[4 * 64];    // Wg^T permuted hi
    __shared__ __align__(16) half4 agl_s[4 * 64];    // Wg^T permuted lo
    __shared__ __align__(16) float bgt_s[64];        // bgt[a][s] = bg[s*4+a]
    __shared__ __align__(16) float bc1_s[HDIM];      // KC*bc1
    __shared__ __align__(16) float bh1_s[HDIM];      // KC*bh1
    __shared__ __align__(16) float ua0_s[4];         // 2*colsum(Wc2) + 2*bc2
    __shared__ float w2b_s;                          // sum(wh2) + bh2

    const int tid = threadIdx.x;

    // ---- per-block pack: raw global weights -> LDS frags ------------------
    // A-frag layout: lane l holds A[m][k], m = l&15, k = (l>>4)*4 + e
    for (int idx = tid; idx < 8 * 64; idx += 256) {
        const int c = idx >> 6, lane = idx & 63;
        const int m = lane & 15, q = lane >> 4;
        half4 hz1, hua, hhp, h2h, h2l, hdh, hdl;
        #pragma unroll
        for (int e = 0; e < 4; ++e) {
            const int k = q * 4 + e;
            const int j = c * 16 + k;
            hz1[e] = (_Float16)(KC * Wc1[k * HDIM + c*16 + m]);
            // ua = const - 4*Wc2^T R1  (const in ua0_s)
            hua[e] = (m < ADIM) ? (_Float16)(-4.0f * Wc2[j * ADIM + m])
                                : (_Float16)0.f;
            // hp MFMA: row 0 = 2*wh2 chunk, rows 1-15 zero
            hhp[e] = (m == 0) ? (_Float16)(2.0f * wh2[j]) : (_Float16)0.f;
            float w2 = KC * Wh1[k * HDIM + c*16 + m];
            _Float16 hh = (_Float16)w2;
            h2h[e] = hh; h2l[e] = (_Float16)(w2 - (float)hh);
            float wd = 4.0f * Wh1[m * HDIM + j] * wh2[j];   // 4x: sech2 = 4*s2'
            _Float16 hd = (_Float16)wd;
            hdh[e] = hd; hdl[e] = (_Float16)(wd - (float)hd);
        }
        az1_s[idx] = hz1;  aua_s[idx] = hua;  ahp_s[idx] = hhp;
        az2h_s[idx] = h2h; az2l_s[idx] = h2l;
        adhh_s[idx] = hdh; adhl_s[idx] = hdl;
    }
    if (tid < 64) {                                  // Wf^T split
        const int m = tid & 15, q = tid >> 4;
        half4 fh, fl;
        #pragma unroll
        for (int e = 0; e < 4; ++e) {
            float w = Wf[(q*4+e) * SDIM + m];
            _Float16 h = (_Float16)w;
            fh[e] = h; fl[e] = (_Float16)(w - (float)h);
        }
        afh_s[tid] = fh; afl_s[tid] = fl;
    }
    {                                                // Wg^T row-permuted split
        const int a = tid >> 6, lane = tid & 63;
        const int m = lane & 15, q = lane >> 4;      // m = s index
        half4 gh, gl;
        #pragma unroll
        for (int e = 0; e < 4; ++e) {
            float w = Wg[(q*4+e) * 64 + m*4 + a];
            _Float16 h = (_Float16)w;
            gh[e] = h; gl[e] = (_Float16)(w - (float)h);
        }
        agh_s[tid] = gh; agl_s[tid] = gl;
    }
    if (tid < 64)                                    // bgt[a][s] = bg[s*4+a]
        bgt_s[(tid >> 4) * 16 + (tid & 15)] = bg[(tid & 15) * 4 + (tid >> 4)];
    if (tid < HDIM) {
        bc1_s[tid] = KC * bc1[tid];
        bh1_s[tid] = KC * bh1[tid];
    }
    if (tid < 4) {                                   // ua const: 2*colsum+2*bc2
        float s = 2.0f * bc2[tid];
        for (int j = 0; j < HDIM; ++j) s += 2.0f * Wc2[j * ADIM + tid];
        ua0_s[tid] = s;
    }
    if (tid == 0) {                                  // W2B = sum(wh2)+bh2
        float s = bh2[0];
        for (int j = 0; j < HDIM; ++j) s += wh2[j];
        w2b_s = s;
    }
    __syncthreads();

    // ---- main: 8 contiguous 16-token tiles per wave -----------------------
    const int lane = tid & 63;
    const int q = lane >> 4, n = lane & 15;
    const int wid = blockIdx.x * WPB + (tid >> 6);

    f32x4 bfC = *(const f32x4*)(bf + q*4);
    f32x4 uaC;                                       // ua const in q0, else 0
    {
        f32x4 u0 = *(const f32x4*)(ua0_s);
        uaC.x = q == 0 ? u0.x : 0.f; uaC.y = q == 0 ? u0.y : 0.f;
        uaC.z = q == 0 ? u0.z : 0.f; uaC.w = q == 0 ? u0.w : 0.f;
    }
    const float w2b = w2b_s;

    for (int it = 0; it < TPW; ++it) {
        const int tile = wid * TPW + it;
        // B-frag of state^T: lane(q,n) holds state[token n][q*4 .. q*4+3]
        f32x4 sv = *(const f32x4*)(state + (size_t)(tile*16 + n) * SDIM + q*4);
        half4 bsh, bsl;
        split4(sv, bsh, bsl);

        // Accumulators: ua 1 chain, dh 2 chains, hp 1 MFMA chain.
        f32x4 uaA  = uaC;
        f32x4 hpA  = {0.f, 0.f, 0.f, 0.f};
        f32x4 dhA  = {0.f, 0.f, 0.f, 0.f};
        f32x4 dhBC = {0.f, 0.f, 0.f, 0.f};
        #pragma unroll 2
        for (int c = 0; c < 8; ++c) {
            // ---- low-precision chain: z1' -> R1 -> ua (O(1) sensitivity)
            f32x4 b1 = *(const f32x4*)(&bc1_s[c*16 + q*4]);
            f32x4 z1 = mm(az1_s[c*64 + lane], bsh, b1);   // = 2log2e * z1
            f32x4 R1 = sigR4(z1);
            uaA = mm(aua_s[c*64 + lane], toh_rtz(R1), uaA);

            // ---- high-precision chain: z2' (split x split, 3 MFMAs)
            f32x4 b2v = *(const f32x4*)(&bh1_s[c*16 + q*4]);
            half4 a2h = az2h_s[c*64 + lane];
            f32x4 z2 = mm(a2h, bsl, b2v);
            z2 = mm(az2l_s[c*64 + lane], bsh, z2);
            z2 = mm(a2h, bsh, z2);                        // = 2log2e * z2
            f32x4 R2 = sigR4(z2);
            // hp via MFMA: row0-only A, B = R2 f16 (D layout == B layout)
            hpA = mm(ahp_s[c*64 + lane], toh_rtz(R2), hpA);
            // s2' = R(1-R) = sech^2/4 (4 folded into adh);  exact-product fma
            f32x4 s2;
            s2.x = __builtin_fmaf(-R2.x, R2.x, R2.x);
            s2.y = __builtin_fmaf(-R2.y, R2.y, R2.y);
            s2.z = __builtin_fmaf(-R2.z, R2.z, R2.z);
            s2.w = __builtin_fmaf(-R2.w, R2.w, R2.w);
            half4 s2h, s2l;
            split4(s2, s2h, s2l);
            half4 adh_h = adhh_s[c*64 + lane];
            dhA  = mm(adh_h, s2h, dhA);
            dhBC = mm(adhl_s[c*64 + lane], s2h, dhBC);
            dhBC = mm(adh_h, s2l, dhBC);
        }
        f32x4 ua = uaA;
        f32x4 dh = dhA + dhBC;
        const float hp = hpA.x;            // complete at q0 (rows 1-15 zero)

        // f^T (rows = s) — split path
        half4 fh = afh_s[lane], fl = afl_s[lane];
        f32x4 fD = mm(fh, bsl, bfC);
        fD = mm(fl, bsh, fD);
        fD = mm(fh, bsh, fD);

        // right = sum(wh2*t2) + bh2 + dh.f = W2B - hp + redq(dh.f)
        float right = w2b - hp + redq(dot4(dh, fD));

        float l0, l1, l2, l3;
        {
            half4 gh = agh_s[0*64 + lane], gl = agl_s[0*64 + lane];
            f32x4 bgC = *(const f32x4*)(&bgt_s[0*16 + q*4]);
            f32x4 G = mm(gh, bsl, bgC); G = mm(gl, bsh, G); G = mm(gh, bsh, G);
            l0 = -redq(dot4(dh, G));
        }
        {
            half4 gh = agh_s[1*64 + lane], gl = agl_s[1*64 + lane];
            f32x4 bgC = *(const f32x4*)(&bgt_s[1*16 + q*4]);
            f32x4 G = mm(gh, bsl, bgC); G = mm(gl, bsh, G); G = mm(gh, bsh, G);
            l1 = -redq(dot4(dh, G));
        }
        {
            half4 gh = agh_s[2*64 + lane], gl = agl_s[2*64 + lane];
            f32x4 bgC = *(const f32x4*)(&bgt_s[2*16 + q*4]);
            f32x4 G = mm(gh, bsl, bgC); G = mm(gl, bsh, G); G = mm(gh, bsh, G);
            l2 = -redq(dot4(dh, G));
        }
        {
            half4 gh = agh_s[3*64 + lane], gl = agl_s[3*64 + lane];
            f32x4 bgC = *(const f32x4*)(&bgt_s[3*16 + q*4]);
            f32x4 G = mm(gh, bsl, bgC); G = mm(gl, bsh, G); G = mm(gh, bsh, G);
            l3 = -redq(dot4(dh, G));
        }

        // ua rows >= 4 zero, const folded: q0 lanes hold complete u_unc.
        float u0 = ua.x, u1 = ua.y, u2 = ua.z, u3 = ua.w;

        float viol = l0*u0 + l1*u1 + l2*u2 + l3*u3 - right;
        float lsq  = l0*l0 + l1*l1 + l2*l2 + l3*l3;
        float lam  = viol > 0.f
                   ? viol * __builtin_amdgcn_rcpf(lsq + 1e-8f) : 0.f;

        if (q == 0) {                      // lanes 0-15 store their token
            f32x4 uo;
            uo.x = u0 - lam*l0; uo.y = u1 - lam*l1;
            uo.z = u2 - lam*l2; uo.w = u3 - lam*l3;
            *(f32x4*)(out + (size_t)(tile*16 + n) * ADIM) = uo;
        }
    }
}

extern "C" void kernel_launch(void* const* d_in, const int* in_sizes, int n_in,
                              void* d_out, int out_size, void* d_ws, size_t ws_size,
                              hipStream_t stream) {
    (void)in_sizes; (void)n_in; (void)d_ws; (void)ws_size; (void)out_size;
    const float* state = (const float*)d_in[0];
    const float* Wc1   = (const float*)d_in[1];
    const float* bc1   = (const float*)d_in[2];
    const float* Wc2   = (const float*)d_in[3];
    const float* bc2   = (const float*)d_in[4];
    const float* Wh1   = (const float*)d_in[5];
    const float* bh1   = (const float*)d_in[6];
    const float* wh2   = (const float*)d_in[7];
    const float* bh2   = (const float*)d_in[8];
    const float* Wf    = (const float*)d_in[9];
    const float* bf    = (const float*)d_in[10];
    const float* Wg    = (const float*)d_in[11];
    const float* bg    = (const float*)d_in[12];
    float* out = (float*)d_out;

    hipLaunchKernelGGL(cbf_qp_kernel, dim3(NBLK), dim3(256), 0, stream,
                       state, Wc1, bc1, Wc2, bc2, Wh1, bh1, wh2, bh2,
                       Wf, bf, Wg, bg, out);
}

// Round 11
// 198.422 us; speedup vs baseline: 1.1621x; 1.0193x over previous
//
#include <hip/hip_runtime.h>
#include <hip/hip_bf16.h>

// B=512, T=2048, S=16, H=128, A=4.  NTOK = 1,048,576 tokens.
// Transposed MFMA chain; tokens live in lanes; D layout == B layout (K16).
// Numerics: BIT-IDENTICAL to r8-verified kernel (absmax 0.125) — all MFMAs
// are 3xK16 split products; only LDS layout (half8 packing) and load
// scheduling (sv prefetch) differ.
// Ledger (measured):
//   (256,4) single-tile body -> no spill, WRITE = 16 MB exactly (r0..r8)
//   r8: 115.4us, VALU 70 + MFMA 34, 3 waves/SIMD, absmax 0.125
//   r9 K32 cat(hi,lo) position-pairing -> absmax 27.5 FAIL.  HK's verified
//   bf16 K32 GEMM loads both A/B contiguous-8 => symmetric layout => my
//   construction should have worked => either f16-K32 layout quirk or
//   shufflevector/half8 plumbing miscompile.  THIS ROUND DISCRIMINATES:
//   same half8+lo4/hi4 plumbing, but K16-only math == r8 bitwise.
//   absmax == 0.125 -> plumbing OK, r9 was layout-semantic (try A-repack).
//   absmax != 0.125 -> plumbing guilty (K32 via union/memcpy next).
// Round-17 deltas vs r8:
//  (m) az2h+az2l -> az2_s half8 {hi,lo}: ONE ds_read_b128/chunk, split via
//      lo4/hi4 (register aliasing, free).  Same for adh {lo,hi}, af, ag.
//      LDS reads 9->7 per chunk (-16/tile).
//  (n) next-tile sv prefetch (hides ~300-500cy L3 latency under split4+c0).
// Kept: KC fold, R-form sech2, hp/ua via R-MFMAs, pkrtz split4, rcp-lam,
// NBLK=2048, biases in LDS, (256,4).  Spill tripwire: WRITE >> 16384 KB.
#define HDIM 128
#define SDIM 16
#define ADIM 4
#define NTOK (512 * 2048)
#define NTILE (NTOK / 16)      // 65536 16-token tiles
#define NBLK 2048
#define WPB 4                  // waves per 256-thread block
#define TPW (NTILE / (NBLK * WPB))   // 8 tiles per wave

#define KC 2.88539008177792681f      // 2*log2(e)

typedef _Float16 half4 __attribute__((ext_vector_type(4)));
typedef _Float16 half8 __attribute__((ext_vector_type(8)));
typedef float f32x4 __attribute__((ext_vector_type(4)));

__device__ __forceinline__ f32x4 mm(half4 a, half4 b, f32x4 c) {
    return __builtin_amdgcn_mfma_f32_16x16x16f16(a, b, c, 0, 0, 0);
}
__device__ __forceinline__ half4 lo4(half8 v) {
    return __builtin_shufflevector(v, v, 0, 1, 2, 3);
}
__device__ __forceinline__ half4 hi4(half8 v) {
    return __builtin_shufflevector(v, v, 4, 5, 6, 7);
}
__device__ __forceinline__ half8 cat(half4 a, half4 b) {
    return __builtin_shufflevector(a, b, 0, 1, 2, 3, 4, 5, 6, 7);
}
// R = 1/(2^z + 1), per element (z PRE-SCALED by 2log2e via packed weights).
// tanh(x) = 1 - 2R;  sech^2(x) = 4R(1-R).
__device__ __forceinline__ f32x4 sigR4(f32x4 z) {
    f32x4 r;
    r.x = __builtin_amdgcn_rcpf(__builtin_amdgcn_exp2f(z.x) + 1.0f);
    r.y = __builtin_amdgcn_rcpf(__builtin_amdgcn_exp2f(z.y) + 1.0f);
    r.z = __builtin_amdgcn_rcpf(__builtin_amdgcn_exp2f(z.z) + 1.0f);
    r.w = __builtin_amdgcn_rcpf(__builtin_amdgcn_exp2f(z.w) + 1.0f);
    return r;
}
__device__ __forceinline__ half4 toh_rtz(f32x4 v) { // packed RTZ, 2 insts
    auto a = __builtin_amdgcn_cvt_pkrtz(v.x, v.y);  // __fp16 x2
    auto b = __builtin_amdgcn_cvt_pkrtz(v.z, v.w);
    half4 h;
    h.x = (_Float16)a.x; h.y = (_Float16)a.y;
    h.z = (_Float16)b.x; h.w = (_Float16)b.y;
    return h;
}
// split fp32 into f16 hi + lo (x ~= hi + lo).  RTZ on hi compensated by lo.
__device__ __forceinline__ void split4(f32x4 v, half4& hi, half4& lo) {
    hi = toh_rtz(v);
    f32x4 r;
    r.x = v.x - (float)hi.x; r.y = v.y - (float)hi.y;
    r.z = v.z - (float)hi.z; r.w = v.w - (float)hi.w;
    lo = toh_rtz(r);
}
__device__ __forceinline__ float dot4(f32x4 a, f32x4 b) {
    return a.x*b.x + a.y*b.y + a.z*b.z + a.w*b.w;
}
__device__ __forceinline__ float redq(float v) {   // sum over the 4 lane-quads
    v += __shfl_xor(v, 16, 64);
    v += __shfl_xor(v, 32, 64);
    return v;
}

__global__ __launch_bounds__(256, 4) void cbf_qp_kernel(
    const float* __restrict__ state,
    const float* __restrict__ Wc1, const float* __restrict__ bc1,
    const float* __restrict__ Wc2, const float* __restrict__ bc2,
    const float* __restrict__ Wh1, const float* __restrict__ bh1,
    const float* __restrict__ wh2, const float* __restrict__ bh2,
    const float* __restrict__ Wf,  const float* __restrict__ bf,
    const float* __restrict__ Wg,  const float* __restrict__ bg,
    float* __restrict__ out)
{
    // ---- LDS weight A-frags ----------------------------------------------
    __shared__ __align__(16) half4 az1_s[8 * 64];    // KC*Wc1^T
    __shared__ __align__(16) half4 aua_s[8 * 64];    // -4*Wc2^T (rows>=4 zero)
    __shared__ __align__(16) half4 ahp_s[8 * 64];    // 2*wh2 row 0, else 0
    __shared__ __align__(16) half8 az2_s[8 * 64];    // {KC*Wh1^T hi, lo}
    __shared__ __align__(16) half8 adh_s[8 * 64];    // {4(Wh1.*wh2) LO, HI}
    __shared__ __align__(16) half8 af_s[64];         // {Wf^T hi, lo}
    __shared__ __align__(16) half8 ag_s[4 * 64];     // {Wg^T perm hi, lo}
    __shared__ __align__(16) float bgt_s[64];        // bgt[a][s] = bg[s*4+a]
    __shared__ __align__(16) float bc1_s[HDIM];      // KC*bc1
    __shared__ __align__(16) float bh1_s[HDIM];      // KC*bh1
    __shared__ __align__(16) float ua0_s[4];         // 2*colsum(Wc2) + 2*bc2
    __shared__ float w2b_s;                          // sum(wh2) + bh2

    const int tid = threadIdx.x;

    // ---- per-block pack: raw global weights -> LDS frags ------------------
    // A-frag layout (K16): lane l holds A[m][k], m = l&15, k = (l>>4)*4 + e
    for (int idx = tid; idx < 8 * 64; idx += 256) {
        const int c = idx >> 6, lane = idx & 63;
        const int m = lane & 15, q = lane >> 4;
        half4 hz1, hua, hhp, h2h, h2l, hdh, hdl;
        #pragma unroll
        for (int e = 0; e < 4; ++e) {
            const int k = q * 4 + e;
            const int j = c * 16 + k;
            hz1[e] = (_Float16)(KC * Wc1[k * HDIM + c*16 + m]);
            hua[e] = (m < ADIM) ? (_Float16)(-4.0f * Wc2[j * ADIM + m])
                                : (_Float16)0.f;
            hhp[e] = (m == 0) ? (_Float16)(2.0f * wh2[j]) : (_Float16)0.f;
            float w2 = KC * Wh1[k * HDIM + c*16 + m];
            _Float16 hh = (_Float16)w2;
            h2h[e] = hh; h2l[e] = (_Float16)(w2 - (float)hh);
            float wd = 4.0f * Wh1[m * HDIM + j] * wh2[j];   // 4x: sech2=4*s2'
            _Float16 hd = (_Float16)wd;
            hdh[e] = hd; hdl[e] = (_Float16)(wd - (float)hd);
        }
        az1_s[idx] = hz1;  aua_s[idx] = hua;  ahp_s[idx] = hhp;
        az2_s[idx] = cat(h2h, h2l);    // {hi, lo}
        adh_s[idx] = cat(hdl, hdh);    // {lo, hi}
    }
    if (tid < 64) {                                  // Wf^T split
        const int m = tid & 15, q = tid >> 4;
        half4 fh, fl;
        #pragma unroll
        for (int e = 0; e < 4; ++e) {
            float w = Wf[(q*4+e) * SDIM + m];
            _Float16 h = (_Float16)w;
            fh[e] = h; fl[e] = (_Float16)(w - (float)h);
        }
        af_s[tid] = cat(fh, fl);
    }
    {                                                // Wg^T row-permuted split
        const int a = tid >> 6, lane = tid & 63;
        const int m = lane & 15, q = lane >> 4;      // m = s index
        half4 gh, gl;
        #pragma unroll
        for (int e = 0; e < 4; ++e) {
            float w = Wg[(q*4+e) * 64 + m*4 + a];
            _Float16 h = (_Float16)w;
            gh[e] = h; gl[e] = (_Float16)(w - (float)h);
        }
        ag_s[tid] = cat(gh, gl);
    }
    if (tid < 64)                                    // bgt[a][s] = bg[s*4+a]
        bgt_s[(tid >> 4) * 16 + (tid & 15)] = bg[(tid & 15) * 4 + (tid >> 4)];
    if (tid < HDIM) {
        bc1_s[tid] = KC * bc1[tid];
        bh1_s[tid] = KC * bh1[tid];
    }
    if (tid < 4) {                                   // ua const: 2*colsum+2*bc2
        float s = 2.0f * bc2[tid];
        for (int j = 0; j < HDIM; ++j) s += 2.0f * Wc2[j * ADIM + tid];
        ua0_s[tid] = s;
    }
    if (tid == 0) {                                  // W2B = sum(wh2)+bh2
        float s = bh2[0];
        for (int j = 0; j < HDIM; ++j) s += wh2[j];
        w2b_s = s;
    }
    __syncthreads();

    // ---- main: 8 contiguous 16-token tiles per wave -----------------------
    const int lane = tid & 63;
    const int q = lane >> 4, n = lane & 15;
    const int wid = blockIdx.x * WPB + (tid >> 6);

    f32x4 bfC = *(const f32x4*)(bf + q*4);
    f32x4 uaC;                                       // ua const in q0, else 0
    {
        f32x4 u0 = *(const f32x4*)(ua0_s);
        uaC.x = q == 0 ? u0.x : 0.f; uaC.y = q == 0 ? u0.y : 0.f;
        uaC.z = q == 0 ? u0.z : 0.f; uaC.w = q == 0 ? u0.w : 0.f;
    }
    const float w2b = w2b_s;

    // prime prefetch
    f32x4 sv = *(const f32x4*)(state + (size_t)(wid*TPW*16 + n) * SDIM + q*4);

    for (int it = 0; it < TPW; ++it) {
        const int tile = wid * TPW + it;
        const int nxt = (it + 1 < TPW) ? tile + 1 : tile;
        f32x4 svn = *(const f32x4*)(state + (size_t)(nxt*16 + n) * SDIM + q*4);

        half4 bsh, bsl;
        split4(sv, bsh, bsl);

        // Accumulators: ua, hp, dhA, dhBC.
        f32x4 uaA  = uaC;
        f32x4 hpA  = {0.f, 0.f, 0.f, 0.f};
        f32x4 dhA  = {0.f, 0.f, 0.f, 0.f};
        f32x4 dhBC = {0.f, 0.f, 0.f, 0.f};
        #pragma unroll 2
        for (int c = 0; c < 8; ++c) {
            // ---- low-precision chain: z1' -> R1 -> ua
            f32x4 b1 = *(const f32x4*)(&bc1_s[c*16 + q*4]);
            f32x4 z1 = mm(az1_s[c*64 + lane], bsh, b1);   // = 2log2e * z1
            f32x4 R1 = sigR4(z1);
            uaA = mm(aua_s[c*64 + lane], toh_rtz(R1), uaA);

            // ---- high-precision chain: z2' (split x split, 3x K16)
            f32x4 b2v = *(const f32x4*)(&bh1_s[c*16 + q*4]);
            half8 a2 = az2_s[c*64 + lane];                // one b128 read
            half4 a2h = lo4(a2), a2l = hi4(a2);
            f32x4 z2 = mm(a2h, bsl, b2v);
            z2 = mm(a2l, bsh, z2);
            z2 = mm(a2h, bsh, z2);                        // = 2log2e * z2
            f32x4 R2 = sigR4(z2);
            // hp via MFMA: row0-only A, B = R2 f16 (D layout == B layout)
            hpA = mm(ahp_s[c*64 + lane], toh_rtz(R2), hpA);
            // s2' = R(1-R) = sech^2/4 (4 folded into adh)
            f32x4 s2;
            s2.x = __builtin_fmaf(-R2.x, R2.x, R2.x);
            s2.y = __builtin_fmaf(-R2.y, R2.y, R2.y);
            s2.z = __builtin_fmaf(-R2.z, R2.z, R2.z);
            s2.w = __builtin_fmaf(-R2.w, R2.w, R2.w);
            half4 s2h, s2l;
            split4(s2, s2h, s2l);
            half8 ad = adh_s[c*64 + lane];                // one b128 read
            half4 adl = lo4(ad), adhh = hi4(ad);
            dhA  = mm(adhh, s2h, dhA);
            dhBC = mm(adl,  s2h, dhBC);
            dhBC = mm(adhh, s2l, dhBC);
        }
        f32x4 ua = uaA;
        f32x4 dh = dhA + dhBC;
        const float hp = hpA.x;            // complete at q0 (rows 1-15 zero)

        // f^T (rows = s) — split path, 3x K16
        half8 af = af_s[lane];
        half4 fh = lo4(af), fl = hi4(af);
        f32x4 fD = mm(fh, bsl, bfC);
        fD = mm(fl, bsh, fD);
        fD = mm(fh, bsh, fD);

        // right = W2B - hp + redq(dh.f)
        float right = w2b - hp + redq(dot4(dh, fD));

        float l0, l1, l2, l3;
        {
            half8 ag = ag_s[0*64 + lane];
            half4 gh = lo4(ag), gl = hi4(ag);
            f32x4 bgC = *(const f32x4*)(&bgt_s[0*16 + q*4]);
            f32x4 G = mm(gh, bsl, bgC); G = mm(gl, bsh, G); G = mm(gh, bsh, G);
            l0 = -redq(dot4(dh, G));
        }
        {
            half8 ag = ag_s[1*64 + lane];
            half4 gh = lo4(ag), gl = hi4(ag);
            f32x4 bgC = *(const f32x4*)(&bgt_s[1*16 + q*4]);
            f32x4 G = mm(gh, bsl, bgC); G = mm(gl, bsh, G); G = mm(gh, bsh, G);
            l1 = -redq(dot4(dh, G));
        }
        {
            half8 ag = ag_s[2*64 + lane];
            half4 gh = lo4(ag), gl = hi4(ag);
            f32x4 bgC = *(const f32x4*)(&bgt_s[2*16 + q*4]);
            f32x4 G = mm(gh, bsl, bgC); G = mm(gl, bsh, G); G = mm(gh, bsh, G);
            l2 = -redq(dot4(dh, G));
        }
        {
            half8 ag = ag_s[3*64 + lane];
            half4 gh = lo4(ag), gl = hi4(ag);
            f32x4 bgC = *(const f32x4*)(&bgt_s[3*16 + q*4]);
            f32x4 G = mm(gh, bsl, bgC); G = mm(gl, bsh, G); G = mm(gh, bsh, G);
            l3 = -redq(dot4(dh, G));
        }

        // ua rows >= 4 zero, const folded: q0 lanes hold complete u_unc.
        float u0 = ua.x, u1 = ua.y, u2 = ua.z, u3 = ua.w;

        float viol = l0*u0 + l1*u1 + l2*u2 + l3*u3 - right;
        float lsq  = l0*l0 + l1*l1 + l2*l2 + l3*l3;
        float lam  = viol > 0.f
                   ? viol * __builtin_amdgcn_rcpf(lsq + 1e-8f) : 0.f;

        if (q == 0) {                      // lanes 0-15 store their token
            f32x4 uo;
            uo.x = u0 - lam*l0; uo.y = u1 - lam*l1;
            uo.z = u2 - lam*l2; uo.w = u3 - lam*l3;
            *(f32x4*)(out + (size_t)(tile*16 + n) * ADIM) = uo;
        }

        sv = svn;
    }
}

extern "C" void kernel_launch(void* const* d_in, const int* in_sizes, int n_in,
                              void* d_out, int out_size, void* d_ws, size_t ws_size,
                              hipStream_t stream) {
    (void)in_sizes; (void)n_in; (void)d_ws; (void)ws_size; (void)out_size;
    const float* state = (const float*)d_in[0];
    const float* Wc1   = (const float*)d_in[1];
    const float* bc1   = (const float*)d_in[2];
    const float* Wc2   = (const float*)d_in[3];
    const float* bc2   = (const float*)d_in[4];
    const float* Wh1   = (const float*)d_in[5];
    const float* bh1   = (const float*)d_in[6];
    const float* wh2   = (const float*)d_in[7];
    const float* bh2   = (const float*)d_in[8];
    const float* Wf    = (const float*)d_in[9];
    const float* bf    = (const float*)d_in[10];
    const float* Wg    = (const float*)d_in[11];
    const float* bg    = (const float*)d_in[12];
    float* out = (float*)d_out;

    hipLaunchKernelGGL(cbf_qp_kernel, dim3(NBLK), dim3(256), 0, stream,
                       state, Wc1, bc1, Wc2, bc2, Wh1, bh1, wh2, bh2,
                       Wf, bf, Wg, bg, out);
}